// Round 3
// baseline (64.664 us; speedup 1.0000x reference)
//
#include <hip/hip_runtime.h>
#include <math.h>

// Shape (fixed by setup_inputs): B=8, S=4096, D=1024, CD=1024
// out = rmsnorm(x) * (1 + scale[b]) + shift[b], [scale|shift] = cq @ wq^T + b_proj
// g[b,d] = rw[d] * (1 + scale[b,d]) precomputed so k_main does x*inv*g + sh.

constexpr int Bn = 8;
constexpr int Sn = 4096;
constexpr int Dn = 1024;
constexpr int TWO_D = 2048;
// ws layout (floats)
constexpr int OFF_PART = 0;      // 2048 partials for |w| reduction
constexpr int OFF_CQ   = 4096;   // 8192: quantized c (8 x 1024)
constexpr int OFF_G    = 16384;  // 8192: rw * (1 + scale)  (8 x 1024)
constexpr int OFF_SH   = 24576;  // 8192: shift (8 x 1024)

using f4 = __attribute__((ext_vector_type(4))) float;

__device__ __forceinline__ float waveReduceSumBcast(float v) {
#pragma unroll
    for (int off = 32; off > 0; off >>= 1) v += __shfl_xor(v, off, 64);
    return v;
}
__device__ __forceinline__ float waveReduceMaxBcast(float v) {
#pragma unroll
    for (int off = 32; off > 0; off >>= 1) v = fmaxf(v, __shfl_xor(v, off, 64));
    return v;
}

// 1) fused preamble: blocks 0..2047 -> |w| partial sums; blocks 2048..2055 -> c-quant
__global__ void k_pre(const float* __restrict__ w, const float* __restrict__ c,
                      float* __restrict__ part, float* __restrict__ cq) {
    int tid = threadIdx.x;
    if (blockIdx.x < TWO_D) {
        size_t base = (size_t)blockIdx.x * 1024 + (size_t)tid * 4;
        f4 v = *(const f4*)(w + base);
        float s = fabsf(v.x) + fabsf(v.y) + fabsf(v.z) + fabsf(v.w);
        s = waveReduceSumBcast(s);
        __shared__ float lds[4];
        if ((tid & 63) == 0) lds[tid >> 6] = s;
        __syncthreads();
        if (tid == 0) part[blockIdx.x] = lds[0] + lds[1] + lds[2] + lds[3];
    } else {
        int b = blockIdx.x - TWO_D;
        f4 v = ((const f4*)(c + (size_t)b * Dn))[tid];
        float m = fmaxf(fmaxf(fabsf(v.x), fabsf(v.y)), fmaxf(fabsf(v.z), fabsf(v.w)));
        m = waveReduceMaxBcast(m);
        __shared__ float lm[4];
        if ((tid & 63) == 0) lm[tid >> 6] = m;
        __syncthreads();
        float mx = fmaxf(fmaxf(lm[0], lm[1]), fmaxf(lm[2], lm[3]));
        float scale = 127.0f / fmaxf(mx, 1e-5f);
        float inv = 1.0f / scale;
        f4 q;
        q.x = fminf(fmaxf(rintf(v.x * scale), -128.0f), 127.0f) * inv;
        q.y = fminf(fmaxf(rintf(v.y * scale), -128.0f), 127.0f) * inv;
        q.z = fminf(fmaxf(rintf(v.z * scale), -128.0f), 127.0f) * inv;
        q.w = fminf(fmaxf(rintf(v.w * scale), -128.0f), 127.0f) * inv;
        ((f4*)(cq + (size_t)b * Dn))[tid] = q;
    }
}

// 2) tiny GEMM: one wave per output row d. All 8 batch dots accumulate in regs,
//    then ONE interleaved butterfly (depth 6, 8-way ILP) reduces all of them.
__global__ void k_emb(const float* __restrict__ w, const float* __restrict__ bp,
                      const float* __restrict__ cq, const float* __restrict__ part,
                      const float* __restrict__ rw,
                      float* __restrict__ g, float* __restrict__ sh) {
    int tid = threadIdx.x;
    // block-wide reduce of partials -> mean(|w|)
    float s = 0.0f;
#pragma unroll
    for (int k = 0; k < 8; ++k) s += part[tid + k * 256];
    s = waveReduceSumBcast(s);
    __shared__ float lds[4];
    if ((tid & 63) == 0) lds[tid >> 6] = s;
    __syncthreads();
    float mw = fmaxf((lds[0] + lds[1] + lds[2] + lds[3]) * (1.0f / 2097152.0f), 1e-5f);
    float sw = 1.0f / mw;

    int lane = tid & 63;
    int d = (blockIdx.x * blockDim.x + tid) >> 6;   // 0..2047
    const float* wr = w + (size_t)d * 1024 + (size_t)lane * 16;
    float t[16];
#pragma unroll
    for (int j = 0; j < 16; j += 4) {
        f4 v = *(const f4*)(wr + j);
        t[j + 0] = fminf(fmaxf(rintf(v.x * sw), -1.0f), 1.0f);
        t[j + 1] = fminf(fmaxf(rintf(v.y * sw), -1.0f), 1.0f);
        t[j + 2] = fminf(fmaxf(rintf(v.z * sw), -1.0f), 1.0f);
        t[j + 3] = fminf(fmaxf(rintf(v.w * sw), -1.0f), 1.0f);
    }
    float acc[Bn];
#pragma unroll
    for (int b = 0; b < Bn; ++b) {
        const float* cr = cq + (size_t)b * Dn + (size_t)lane * 16;
        float dot = 0.0f;
#pragma unroll
        for (int j = 0; j < 16; j += 4) {
            f4 u = *(const f4*)(cr + j);
            dot += t[j + 0] * u.x + t[j + 1] * u.y + t[j + 2] * u.z + t[j + 3] * u.w;
        }
        acc[b] = dot;
    }
    // interleaved butterfly: depth 6, 8 independent chains
#pragma unroll
    for (int off = 32; off > 0; off >>= 1) {
#pragma unroll
        for (int b = 0; b < Bn; ++b) acc[b] += __shfl_xor(acc[b], off, 64);
    }
    if (lane == 0) {
        float bias = bp[d];
        if (d < Dn) {
            float rwd = rw[d];
#pragma unroll
            for (int b = 0; b < Bn; ++b)
                g[b * Dn + d] = rwd * (1.0f + (acc[b] * mw + bias));
        } else {
#pragma unroll
            for (int b = 0; b < Bn; ++b)
                sh[b * Dn + (d - Dn)] = acc[b] * mw + bias;
        }
    }
}

// 3) main fused pass: 2048 blocks x 4 waves; each wave does 4 rows with
//    next-row prefetch so x-loads overlap the reduce chain. NT loads for x.
__global__ void __launch_bounds__(256) k_main(
        const float* __restrict__ x, const float* __restrict__ g,
        const float* __restrict__ sh, float* __restrict__ out) {
    constexpr int NW = 2048 * 4;               // total waves
    int tid  = threadIdx.x;
    int lane = tid & 63;
    int row  = blockIdx.x * 4 + (tid >> 6);    // first row for this wave

    const f4* xr = (const f4*)(x + (size_t)row * Dn);
    f4 v0 = __builtin_nontemporal_load(&xr[lane]);
    f4 v1 = __builtin_nontemporal_load(&xr[lane + 64]);
    f4 v2 = __builtin_nontemporal_load(&xr[lane + 128]);
    f4 v3 = __builtin_nontemporal_load(&xr[lane + 192]);

#pragma unroll
    for (int it = 0; it < 4; ++it) {
        int nrow = row + NW;
        f4 n0, n1, n2, n3;
        if (it < 3) {
            const f4* xn = (const f4*)(x + (size_t)nrow * Dn);
            n0 = __builtin_nontemporal_load(&xn[lane]);
            n1 = __builtin_nontemporal_load(&xn[lane + 64]);
            n2 = __builtin_nontemporal_load(&xn[lane + 128]);
            n3 = __builtin_nontemporal_load(&xn[lane + 192]);
        }
        float ss = v0.x*v0.x + v0.y*v0.y + v0.z*v0.z + v0.w*v0.w
                 + v1.x*v1.x + v1.y*v1.y + v1.z*v1.z + v1.w*v1.w
                 + v2.x*v2.x + v2.y*v2.y + v2.z*v2.z + v2.w*v2.w
                 + v3.x*v3.x + v3.y*v3.y + v3.z*v3.z + v3.w*v3.w;
        ss = waveReduceSumBcast(ss);
        float inv = rsqrtf(ss * (1.0f / 1024.0f) + 1e-6f);

        int b = row >> 12;
        const f4* gv  = (const f4*)(g  + (size_t)b * Dn);
        const f4* s0v = (const f4*)(sh + (size_t)b * Dn);
        f4* ov = (f4*)(out + (size_t)row * Dn);
#pragma unroll
        for (int q = 0; q < 4; ++q) {
            int idx = lane + q * 64;
            f4 v = (q == 0) ? v0 : (q == 1) ? v1 : (q == 2) ? v2 : v3;
            f4 gg = gv[idx];
            f4 s0 = s0v[idx];
            f4 o;
            o.x = v.x * inv * gg.x + s0.x;
            o.y = v.y * inv * gg.y + s0.y;
            o.z = v.z * inv * gg.z + s0.z;
            o.w = v.w * inv * gg.w + s0.w;
            ov[idx] = o;
        }
        if (it < 3) { v0 = n0; v1 = n1; v2 = n2; v3 = n3; row = nrow; }
    }
}

extern "C" void kernel_launch(void* const* d_in, const int* in_sizes, int n_in,
                              void* d_out, int out_size, void* d_ws, size_t ws_size,
                              hipStream_t stream) {
    const float* x  = (const float*)d_in[0];
    const float* c  = (const float*)d_in[1];
    const float* w  = (const float*)d_in[2];
    const float* bp = (const float*)d_in[3];
    const float* rw = (const float*)d_in[4];
    float* out = (float*)d_out;
    float* ws  = (float*)d_ws;

    float* part = ws + OFF_PART;
    float* cq   = ws + OFF_CQ;
    float* g    = ws + OFF_G;
    float* sh   = ws + OFF_SH;

    k_pre <<<TWO_D + Bn, 256, 0, stream>>>(w, c, part, cq);
    k_emb <<<TWO_D / 4, 256, 0, stream>>>(w, bp, cq, part, rw, g, sh);
    k_main<<<TWO_D, 256, 0, stream>>>(x, g, sh, out);
}

// Round 5
// 61.181 us; speedup vs baseline: 1.0569x; 1.0569x over previous
//
#include <hip/hip_runtime.h>
#include <math.h>

// Shape (fixed): B=8, S=4096, D=1024, CD=1024
// out = rmsnorm(x) * (1 + scale[b]) + shift[b], [scale|shift] = cq @ wq^T + b_proj
// g[b,d] = rw[d]*(1+scale[b,d]) precomputed; k_main: out = x*inv*g + sh.

constexpr int Bn = 8;
constexpr int Dn = 1024;
constexpr int TWO_D = 2048;
// ws layout (floats)
constexpr int OFF_PART = 0;      // 2048 partials for |w| reduction
constexpr int OFF_CQ   = 4096;   // 8192: quantized c (8 x 1024)
constexpr int OFF_G    = 16384;  // 8192: rw * (1 + scale)  (8 x 1024)
constexpr int OFF_SH   = 24576;  // 8192: shift (8 x 1024)

using f4 = __attribute__((ext_vector_type(4))) float;

__device__ __forceinline__ float wsumf(float v) {
#pragma unroll
    for (int o = 32; o > 0; o >>= 1) v += __shfl_xor(v, o, 64);
    return v;
}
__device__ __forceinline__ float wmaxf(float v) {
#pragma unroll
    for (int o = 32; o > 0; o >>= 1) v = fmaxf(v, __shfl_xor(v, o, 64));
    return v;
}
__device__ __forceinline__ float sumsq4(f4 v) {
    return v.x*v.x + v.y*v.y + v.z*v.z + v.w*v.w;
}

// 1) fused preamble: blocks 0..2047 -> |w| partial sums; blocks 2048..2055 -> c-quant
__global__ void k_pre(const float* __restrict__ w, const float* __restrict__ c,
                      float* __restrict__ part, float* __restrict__ cq) {
    int tid = threadIdx.x;
    if (blockIdx.x < TWO_D) {
        size_t base = (size_t)blockIdx.x * 1024 + (size_t)tid * 4;
        f4 v = *(const f4*)(w + base);
        float s = fabsf(v.x) + fabsf(v.y) + fabsf(v.z) + fabsf(v.w);
        s = wsumf(s);
        __shared__ float lds[4];
        if ((tid & 63) == 0) lds[tid >> 6] = s;
        __syncthreads();
        if (tid == 0) part[blockIdx.x] = lds[0] + lds[1] + lds[2] + lds[3];
    } else {
        int b = blockIdx.x - TWO_D;
        f4 v = ((const f4*)(c + (size_t)b * Dn))[tid];
        float m = fmaxf(fmaxf(fabsf(v.x), fabsf(v.y)), fmaxf(fabsf(v.z), fabsf(v.w)));
        m = wmaxf(m);
        __shared__ float lm[4];
        if ((tid & 63) == 0) lm[tid >> 6] = m;
        __syncthreads();
        float mx = fmaxf(fmaxf(lm[0], lm[1]), fmaxf(lm[2], lm[3]));
        float scale = 127.0f / fmaxf(mx, 1e-5f);
        float inv = 1.0f / scale;
        f4 q;
        q.x = fminf(fmaxf(rintf(v.x * scale), -128.0f), 127.0f) * inv;
        q.y = fminf(fmaxf(rintf(v.y * scale), -128.0f), 127.0f) * inv;
        q.z = fminf(fmaxf(rintf(v.z * scale), -128.0f), 127.0f) * inv;
        q.w = fminf(fmaxf(rintf(v.w * scale), -128.0f), 127.0f) * inv;
        ((f4*)(cq + (size_t)b * Dn))[tid] = q;
    }
}

// 2) tiny GEMM: one wave per output row d; 8 batch dots in regs, one
//    interleaved butterfly. Writes g = rw*(1+scale) and sh = shift.
__global__ void k_emb(const float* __restrict__ w, const float* __restrict__ bp,
                      const float* __restrict__ cq, const float* __restrict__ part,
                      const float* __restrict__ rw,
                      float* __restrict__ g, float* __restrict__ sh) {
    int tid = threadIdx.x;
    float s = 0.0f;
#pragma unroll
    for (int k = 0; k < 8; ++k) s += part[tid + k * 256];
    s = wsumf(s);
    __shared__ float lds[4];
    if ((tid & 63) == 0) lds[tid >> 6] = s;
    __syncthreads();
    float mw = fmaxf((lds[0] + lds[1] + lds[2] + lds[3]) * (1.0f / 2097152.0f), 1e-5f);
    float sw = 1.0f / mw;

    int lane = tid & 63;
    int d = (blockIdx.x * blockDim.x + tid) >> 6;   // 0..2047
    const float* wr = w + (size_t)d * 1024 + (size_t)lane * 16;
    float t[16];
#pragma unroll
    for (int j = 0; j < 16; j += 4) {
        f4 v = *(const f4*)(wr + j);
        t[j + 0] = fminf(fmaxf(rintf(v.x * sw), -1.0f), 1.0f);
        t[j + 1] = fminf(fmaxf(rintf(v.y * sw), -1.0f), 1.0f);
        t[j + 2] = fminf(fmaxf(rintf(v.z * sw), -1.0f), 1.0f);
        t[j + 3] = fminf(fmaxf(rintf(v.w * sw), -1.0f), 1.0f);
    }
    float acc[Bn];
#pragma unroll
    for (int b = 0; b < Bn; ++b) {
        const float* cr = cq + (size_t)b * Dn + (size_t)lane * 16;
        float dot = 0.0f;
#pragma unroll
        for (int j = 0; j < 16; j += 4) {
            f4 u = *(const f4*)(cr + j);
            dot += t[j + 0] * u.x + t[j + 1] * u.y + t[j + 2] * u.z + t[j + 3] * u.w;
        }
        acc[b] = dot;
    }
#pragma unroll
    for (int o = 32; o > 0; o >>= 1) {
#pragma unroll
        for (int b = 0; b < Bn; ++b) acc[b] += __shfl_xor(acc[b], o, 64);
    }
    if (lane == 0) {
        float bias = bp[d];
        if (d < Dn) {
            float rwd = rw[d];
#pragma unroll
            for (int b = 0; b < Bn; ++b)
                g[b * Dn + d] = rwd * (1.0f + (acc[b] * mw + bias));
        } else {
#pragma unroll
            for (int b = 0; b < Bn; ++b)
                sh[b * Dn + (d - Dn)] = acc[b] * mw + bias;
        }
    }
}

// 3) main fused pass: 2 rows per wave (4096 blocks x 4 waves). The two rows'
//    shuffle-reduce chains interleave (2-way ILP); rows share one g/sh stream.
//    g/h loaded per-quadrant in the apply loop to keep VGPR low.
__global__ void __launch_bounds__(256) k_main(
        const float* __restrict__ x, const float* __restrict__ g,
        const float* __restrict__ sh, float* __restrict__ out) {
    int tid  = threadIdx.x;
    int lane = tid & 63;
    int row  = blockIdx.x * 8 + (tid >> 6) * 2;   // even; rows row, row+1
    int b    = row >> 12;

    const f4* xa = (const f4*)(x + (size_t)row * Dn);
    const f4* xb = xa + 256;
    f4 a0 = xa[lane], a1 = xa[lane+64], a2 = xa[lane+128], a3 = xa[lane+192];
    f4 b0 = xb[lane], b1 = xb[lane+64], b2 = xb[lane+128], b3 = xb[lane+192];

    float sa = sumsq4(a0) + sumsq4(a1) + sumsq4(a2) + sumsq4(a3);
    float sb = sumsq4(b0) + sumsq4(b1) + sumsq4(b2) + sumsq4(b3);
#pragma unroll
    for (int o = 32; o > 0; o >>= 1) {
        sa += __shfl_xor(sa, o, 64);
        sb += __shfl_xor(sb, o, 64);
    }
    float ia = rsqrtf(sa * (1.0f / 1024.0f) + 1e-6f);
    float ib = rsqrtf(sb * (1.0f / 1024.0f) + 1e-6f);

    const f4* gv = (const f4*)(g  + (size_t)b * Dn);
    const f4* hv = (const f4*)(sh + (size_t)b * Dn);
    f4* oa = (f4*)(out + (size_t)row * Dn);
    f4* ob = oa + 256;

#pragma unroll
    for (int q = 0; q < 4; ++q) {
        int idx = lane + q * 64;
        f4 va = (q == 0) ? a0 : (q == 1) ? a1 : (q == 2) ? a2 : a3;
        f4 vb = (q == 0) ? b0 : (q == 1) ? b1 : (q == 2) ? b2 : b3;
        f4 gg = gv[idx];
        f4 hh = hv[idx];
        f4 o;
        o.x = va.x * ia * gg.x + hh.x;
        o.y = va.y * ia * gg.y + hh.y;
        o.z = va.z * ia * gg.z + hh.z;
        o.w = va.w * ia * gg.w + hh.w;
        oa[idx] = o;
        o.x = vb.x * ib * gg.x + hh.x;
        o.y = vb.y * ib * gg.y + hh.y;
        o.z = vb.z * ib * gg.z + hh.z;
        o.w = vb.w * ib * gg.w + hh.w;
        ob[idx] = o;
    }
}

extern "C" void kernel_launch(void* const* d_in, const int* in_sizes, int n_in,
                              void* d_out, int out_size, void* d_ws, size_t ws_size,
                              hipStream_t stream) {
    const float* x  = (const float*)d_in[0];
    const float* c  = (const float*)d_in[1];
    const float* w  = (const float*)d_in[2];
    const float* bp = (const float*)d_in[3];
    const float* rw = (const float*)d_in[4];
    float* out = (float*)d_out;
    float* ws  = (float*)d_ws;

    float* part = ws + OFF_PART;
    float* cq   = ws + OFF_CQ;
    float* g    = ws + OFF_G;
    float* sh   = ws + OFF_SH;

    k_pre <<<TWO_D + Bn, 256, 0, stream>>>(w, c, part, cq);
    k_emb <<<TWO_D / 4, 256, 0, stream>>>(w, bp, cq, part, rw, g, sh);
    k_main<<<Bn * 4096 / 8, 256, 0, stream>>>(x, g, sh, out);
}